// Round 2
// baseline (713.523 us; speedup 1.0000x reference)
//
#include <hip/hip_runtime.h>
#include <hip/hip_bf16.h>
#include <stdint.h>
#include <stddef.h>

// GroupViT assign-attention, MI355X/gfx950. All I/O fp32.
// Identities:
//   raw_attn = (q @ k_w) . key_n + q . k_b          -> no k-projection GEMM
//   fwd attn value = one_hot(argmax)/(cnt+1)        -> no v-projection GEMM
//   out_pre = (sum_assigned key_n)/(cnt+1) @ v_w^T + cnt/(cnt+1) v_b
// Logit precision: W2 fp32, q~ fp32 (VALU GEMM), q~ 3-way bf16 split,
// key 2-way split, 4-product MFMA -> logit err ~7e-6 pre-scale (= ref noise).

using bf16 = __hip_bfloat16;
typedef __attribute__((ext_vector_type(4))) float f32x4;
typedef __attribute__((ext_vector_type(8))) short s16x8;
typedef __attribute__((ext_vector_type(4))) short s16x4;

#define B_  32
#define G_  64
#define N_  4096
#define C_  384
#define SCALE 0.05103103630798287f   // 384^-0.5

__device__ __forceinline__ float us2f(unsigned short u){
  union { unsigned int i; float f; } v; v.i = ((unsigned int)u) << 16; return v.f;
}
__device__ __forceinline__ unsigned short f2us(float f){
  bf16 h = __float2bfloat16(f);
  return __builtin_bit_cast(unsigned short, h);
}

__device__ __forceinline__ f32x4 mfma16(s16x8 a, s16x8 b, f32x4 c){
  return __builtin_amdgcn_mfma_f32_16x16x32_bf16(a, b, c, 0, 0, 0);
}

// Swizzled LDS layout for [rows][64] bf16 tiles: 16B granule q XOR'd with m&7.
__device__ __forceinline__ int loff(int m, int q){ return m*64 + ((q ^ (m & 7)) << 3); }

// Stage ROWS x 64 bf16 tile from row-major bf16 global (ld elements).
template<int ROWS>
__device__ __forceinline__ void stage64(short* lds, const unsigned short* g, int ld, int tid){
  #pragma unroll
  for (int j = 0; j < (ROWS*8)/256; ++j){
    int i = tid + j*256;
    int m = i >> 3, q = i & 7;
    s16x8 v = *(const s16x8*)(g + (size_t)m*ld + q*8);
    *(s16x8*)(lds + loff(m, q)) = v;
  }
}

// Stage ROWS x 64 tile from fp32 global, converting to bf16 (round-nearest).
template<int ROWS>
__device__ __forceinline__ void stage64f(short* lds, const float* g, int ld, int tid){
  #pragma unroll
  for (int j = 0; j < (ROWS*16)/256; ++j){
    int i = tid + j*256;
    int m = i >> 4, qq = i & 15;
    f32x4 v = *(const f32x4*)(g + (size_t)m*ld + qq*4);
    s16x4 h;
    #pragma unroll
    for (int r = 0; r < 4; ++r) h[r] = (short)f2us(v[r]);
    *(s16x4*)(lds + loff(m, qq >> 1) + (qq & 1)*4) = h;
  }
}

// A/B fragment: lane holds row (base + lane&15), k-granule ks*4 + (lane>>4).
__device__ __forceinline__ s16x8 fragld(const short* lds, int row, int ks, int lane){
  return *(const s16x8*)(lds + loff(row + (lane & 15), ks*4 + (lane >> 4)));
}

// ---------------- K0: W2[c][t] = sum_i qw[i,c]*kw[i,t] (fp32) + u, b2v, qbkb
__global__ void k_w2(const float* __restrict__ qw, const float* __restrict__ kw,
                     const float* __restrict__ qb, const float* __restrict__ kb,
                     float* __restrict__ w2f, float* __restrict__ u,
                     float* __restrict__ b2v, float* __restrict__ qbkb)
{
  int c = blockIdx.x, t = threadIdx.x;
  float acc = 0.f;
  #pragma unroll 8
  for (int i = 0; i < 384; ++i)
    acc = fmaf(qw[i*384 + c], kw[i*384 + t], acc);
  w2f[c*384 + t] = acc;

  __shared__ float red[384];
  if (c == 0){
    float a = 0.f, bs = 0.f;
    #pragma unroll 8
    for (int i = 0; i < 384; ++i){
      a  = fmaf(qw[i*384 + t], kb[i], a);
      bs = fmaf(qb[i], kw[i*384 + t], bs);
    }
    u[t] = a; b2v[t] = bs;
    red[t] = qb[t] * kb[t];
    __syncthreads();
    for (int s = 192; s >= 3; s >>= 1){
      if (t < s) red[t] += red[t + s];
      __syncthreads();
    }
    if (t == 0) *qbkb = red[0] + red[1] + red[2];
  }
}

// ---------------- K1: q~ = (query @ W2 + b2) * scale, fp32 VALU, 3-way split
__global__ __launch_bounds__(384) void k_qtf(
    const float* __restrict__ query,   // [2048][384]
    const float* __restrict__ w2f,     // [c][t]
    const float* __restrict__ b2v,
    unsigned short* __restrict__ qt)   // [B][192][384]: rows g=hi, 64+g=mid, 128+g=lo
{
  __shared__ float qs[8*384];
  int m0 = blockIdx.x * 8, t = threadIdx.x;
  #pragma unroll
  for (int r = 0; r < 8; ++r) qs[r*384 + t] = query[(size_t)(m0 + r)*384 + t];
  __syncthreads();
  float acc[8];
  float b2 = b2v[t];
  #pragma unroll
  for (int r = 0; r < 8; ++r) acc[r] = b2;
  for (int c = 0; c < 384; ++c){
    float w = w2f[c*384 + t];
    #pragma unroll
    for (int r = 0; r < 8; ++r) acc[r] = fmaf(qs[r*384 + c], w, acc[r]);
  }
  #pragma unroll
  for (int r = 0; r < 8; ++r){
    int m = m0 + r, b = m >> 6, g = m & 63;
    float v = acc[r] * SCALE;
    unsigned short h = f2us(v);
    float rem = v - us2f(h);
    unsigned short md = f2us(rem);
    float rem2 = rem - us2f(md);
    unsigned short l = f2us(rem2);
    size_t base = ((size_t)b*192 + g)*384 + t;
    qt[base]                   = h;
    qt[base + (size_t)64*384]  = md;
    qt[base + (size_t)128*384] = l;
  }
}

// ---------------- K1b: bias[m] = scale*(query[m].u + q_b.k_b)
__global__ void k_bias(const float* __restrict__ query,
                       const float* __restrict__ u,
                       const float* __restrict__ qbkb,
                       float* __restrict__ bias)
{
  int lane = threadIdx.x & 63, w = threadIdx.x >> 6;
  int m = blockIdx.x*4 + w;
  float p = 0.f;
  #pragma unroll
  for (int j = 0; j < 6; ++j){
    int e = lane + 64*j;
    p = fmaf(query[(size_t)m*384 + e], u[e], p);
  }
  p += __shfl_xor(p, 1);  p += __shfl_xor(p, 2);  p += __shfl_xor(p, 4);
  p += __shfl_xor(p, 8);  p += __shfl_xor(p, 16); p += __shfl_xor(p, 32);
  if (lane == 0) bias[m] = SCALE * (p + *qbkb);
}

// ---------------- K2: logits (4-product split MFMA) + softmax(g) + argmax
__global__ __launch_bounds__(256, 2) void k_attn(
    const unsigned short* __restrict__ qt,    // [B][192][384] bf16
    const float* __restrict__ key,            // [B][N][C] fp32
    const float* __restrict__ bias,           // [B*64]
    float* __restrict__ soft,                 // [B][64][N] fp32
    unsigned char* __restrict__ idx,          // [B][N]
    int* __restrict__ cnt)                    // [B*64]
{
  __shared__ short As[192*64];   // q~ hi/mid/lo tiles
  __shared__ short Bs[256*64];   // key hi, then key lo
  int b = blockIdx.y, n0 = blockIdx.x*256;
  int tid = threadIdx.x, lane = tid & 63, w = tid >> 6;
  const unsigned short* qb = qt + (size_t)b*192*384;
  const float* kb = key + ((size_t)b*N_ + n0)*C_;
  f32x4 acc[4][4] = {};
  float biasv[16];
  #pragma unroll
  for (int mi = 0; mi < 4; ++mi)
    #pragma unroll
    for (int r = 0; r < 4; ++r)
      biasv[mi*4 + r] = bias[b*64 + mi*16 + ((lane >> 4) << 2) + r];

  for (int kk = 0; kk < 6; ++kk){
    f32x4 kv[16];
    #pragma unroll
    for (int j = 0; j < 16; ++j){
      int i = tid + j*256, m = i >> 4, qq = i & 15;
      kv[j] = *(const f32x4*)(kb + (size_t)m*C_ + kk*64 + qq*4);
    }
    stage64<192>(As, qb + kk*64, 384, tid);
    #pragma unroll
    for (int j = 0; j < 16; ++j){
      int i = tid + j*256, m = i >> 4, qq = i & 15;
      s16x4 h;
      #pragma unroll
      for (int r = 0; r < 4; ++r) h[r] = (short)f2us(kv[j][r]);
      *(s16x4*)(Bs + loff(m, qq >> 1) + (qq & 1)*4) = h;
    }
    __syncthreads();
    // phase A: (qh + qm + ql) . kh
    #pragma unroll
    for (int ks = 0; ks < 2; ++ks){
      s16x8 bf4[4];
      #pragma unroll
      for (int ni = 0; ni < 4; ++ni) bf4[ni] = fragld(Bs, w*64 + ni*16, ks, lane);
      #pragma unroll
      for (int mi = 0; mi < 4; ++mi){
        s16x8 a0 = fragld(As, mi*16, ks, lane);
        s16x8 a1 = fragld(As, 64 + mi*16, ks, lane);
        s16x8 a2 = fragld(As, 128 + mi*16, ks, lane);
        #pragma unroll
        for (int ni = 0; ni < 4; ++ni){
          acc[mi][ni] = mfma16(a0, bf4[ni], acc[mi][ni]);
          acc[mi][ni] = mfma16(a1, bf4[ni], acc[mi][ni]);
          acc[mi][ni] = mfma16(a2, bf4[ni], acc[mi][ni]);
        }
      }
    }
    __syncthreads();
    // stage key lo
    #pragma unroll
    for (int j = 0; j < 16; ++j){
      int i = tid + j*256, m = i >> 4, qq = i & 15;
      s16x4 l;
      #pragma unroll
      for (int r = 0; r < 4; ++r){
        float f = kv[j][r];
        l[r] = (short)f2us(f - us2f(f2us(f)));
      }
      *(s16x4*)(Bs + loff(m, qq >> 1) + (qq & 1)*4) = l;
    }
    __syncthreads();
    // phase B: qh . kl
    #pragma unroll
    for (int ks = 0; ks < 2; ++ks){
      s16x8 bf4[4];
      #pragma unroll
      for (int ni = 0; ni < 4; ++ni) bf4[ni] = fragld(Bs, w*64 + ni*16, ks, lane);
      #pragma unroll
      for (int mi = 0; mi < 4; ++mi){
        s16x8 a0 = fragld(As, mi*16, ks, lane);
        #pragma unroll
        for (int ni = 0; ni < 4; ++ni)
          acc[mi][ni] = mfma16(a0, bf4[ni], acc[mi][ni]);
      }
    }
    __syncthreads();
  }

  #pragma unroll 1
  for (int ni = 0; ni < 4; ++ni){
    int col = n0 + w*64 + ni*16 + (lane & 15);
    float sg[16];
    float mx = -3.4e38f;
    #pragma unroll
    for (int i = 0; i < 16; ++i){
      float v = acc[i >> 2][ni][i & 3] + biasv[i];
      sg[i] = v; mx = fmaxf(mx, v);
    }
    mx = fmaxf(mx, __shfl_xor(mx, 16));
    mx = fmaxf(mx, __shfl_xor(mx, 32));
    float sum = 0.f, bv = -3.4e38f; int bg = 0;
    #pragma unroll
    for (int i = 0; i < 16; ++i){
      int g = (i >> 2)*16 + ((lane >> 4) << 2) + (i & 3);
      float v = sg[i];
      if (v > bv){ bv = v; bg = g; }
      float e = __expf(v - mx);
      sg[i] = e; sum += e;
    }
    sum += __shfl_xor(sum, 16);
    sum += __shfl_xor(sum, 32);
    { float ov = __shfl_xor(bv, 16); int og = __shfl_xor(bg, 16);
      if (ov > bv || (ov == bv && og < bg)){ bv = ov; bg = og; } }
    { float ov = __shfl_xor(bv, 32); int og = __shfl_xor(bg, 32);
      if (ov > bv || (ov == bv && og < bg)){ bv = ov; bg = og; } }
    float inv = 1.0f / sum;
    #pragma unroll
    for (int i = 0; i < 16; ++i){
      int g = (i >> 2)*16 + ((lane >> 4) << 2) + (i & 3);
      soft[(size_t)(b*64 + g)*N_ + col] = sg[i] * inv;
    }
    if ((lane >> 4) == 0){
      idx[(size_t)b*N_ + col] = (unsigned char)bg;
      atomicAdd(&cnt[b*64 + bg], 1);
    }
  }
}

// ---------------- K3: agg[b,g,c] = sum of key rows assigned to g
__global__ __launch_bounds__(192) void k_agg(
    const float* __restrict__ key,
    const unsigned char* __restrict__ idx,
    float* __restrict__ agg)                  // [2048][384] fp32, pre-zeroed
{
  __shared__ float accs[64*192];
  __shared__ unsigned char gl[512];
  int ch = blockIdx.x;       // 0..7 (512-row chunk)
  int h  = blockIdx.y;       // 0..1 (channel half)
  int b  = blockIdx.z;
  int t  = threadIdx.x;      // channel h*192+t
  for (int i = t; i < 64*192; i += 192) accs[i] = 0.f;
  const unsigned char* ib = idx + (size_t)b*N_ + ch*512;
  for (int i = t; i < 128; i += 192) ((unsigned int*)gl)[i] = ((const unsigned int*)ib)[i];
  __syncthreads();
  const float* kp = key + ((size_t)b*N_ + ch*512)*C_ + h*192 + t;
  for (int n0b = 0; n0b < 512; n0b += 8){
    float v[8];
    #pragma unroll
    for (int r = 0; r < 8; ++r) v[r] = kp[(size_t)(n0b + r)*C_];
    #pragma unroll
    for (int r = 0; r < 8; ++r) accs[(int)gl[n0b + r]*192 + t] += v[r];
  }
  __syncthreads();
  float* ab = agg + (size_t)b*64*C_ + h*192 + t;
  for (int gg = 0; gg < 64; ++gg)
    atomicAdd(ab + (size_t)gg*C_, accs[gg*192 + t]);
}

// ---------------- K3b: aggs = bf16(agg/(cnt+1))
__global__ void k_scale(const float* __restrict__ agg,
                        const int* __restrict__ cnt,
                        unsigned short* __restrict__ aggs)
{
  int m = blockIdx.x, t = threadIdx.x;
  float inv = 1.f / ((float)cnt[m] + 1.f);
  aggs[(size_t)m*384 + t] = f2us(agg[(size_t)m*384 + t] * inv);
}

// ---------------- K4: out = A @ W^T + bias-term (mode 0: +cw*v_b -> bf16 tbuf;
//                                                 mode 1: +p_b   -> fp32 out)
__global__ __launch_bounds__(256) void k_out384(
    const unsigned short* __restrict__ A,     // [2048][384] bf16
    const float* __restrict__ Wm,             // [384][384] fp32, [n][k]
    const float* __restrict__ bvec,           // [384] fp32
    const int* __restrict__ cnt,
    unsigned short* __restrict__ outb,
    float* __restrict__ outf,
    int mode)
{
  __shared__ short As[128*64];
  __shared__ short Bs[128*64];
  __shared__ float cwl[128];
  int m0 = blockIdx.y*128, nn0 = blockIdx.x*128;
  int tid = threadIdx.x, lane = tid & 63, w = tid >> 6;
  f32x4 acc[8][2] = {};
  for (int kk = 0; kk < 6; ++kk){
    stage64<128>(As, A + (size_t)m0*384 + kk*64, 384, tid);
    stage64f<128>(Bs, Wm + (size_t)nn0*384 + kk*64, 384, tid);
    __syncthreads();
    #pragma unroll
    for (int ks = 0; ks < 2; ++ks){
      s16x8 af[8], bfr[2];
      #pragma unroll
      for (int mi = 0; mi < 8; ++mi) af[mi] = fragld(As, mi*16, ks, lane);
      #pragma unroll
      for (int ni = 0; ni < 2; ++ni) bfr[ni] = fragld(Bs, w*32 + ni*16, ks, lane);
      #pragma unroll
      for (int mi = 0; mi < 8; ++mi)
        #pragma unroll
        for (int ni = 0; ni < 2; ++ni)
          acc[mi][ni] = mfma16(af[mi], bfr[ni], acc[mi][ni]);
    }
    __syncthreads();
  }
  if (mode == 0 && tid < 128){
    float c = (float)cnt[m0 + tid];
    cwl[tid] = c / (c + 1.f);
  }
  __syncthreads();
  #pragma unroll
  for (int ni = 0; ni < 2; ++ni){
    int n = nn0 + w*32 + ni*16 + (lane & 15);
    float bb = bvec[n];
    #pragma unroll
    for (int mi = 0; mi < 8; ++mi){
      #pragma unroll
      for (int r = 0; r < 4; ++r){
        int ml = mi*16 + ((lane >> 4) << 2) + r;
        float v = acc[mi][ni][r];
        if (mode == 0){
          v += cwl[ml] * bb;
          outb[(size_t)(m0 + ml)*384 + n] = f2us(v);
        } else {
          outf[(size_t)(m0 + ml)*384 + n] = v + bb;
        }
      }
    }
  }
}

extern "C" void kernel_launch(void* const* d_in, const int* in_sizes, int n_in,
                              void* d_out, int out_size, void* d_ws, size_t ws_size,
                              hipStream_t stream)
{
  const float* query = (const float*)d_in[0];
  const float* key   = (const float*)d_in[1];
  const float* qw    = (const float*)d_in[2];
  const float* qb    = (const float*)d_in[3];
  const float* kw    = (const float*)d_in[4];
  const float* kb    = (const float*)d_in[5];
  const float* vw    = (const float*)d_in[6];
  const float* vb    = (const float*)d_in[7];
  const float* pw    = (const float*)d_in[8];
  const float* pb    = (const float*)d_in[9];

  char* ws = (char*)d_ws;
  float* w2f          = (float*)(ws + 0);                  // 589824
  float* u            = (float*)(ws + 589824);             // 1536
  float* b2v          = (float*)(ws + 591360);             // 1536
  float* qbkb         = (float*)(ws + 592896);             // 256
  float* bias         = (float*)(ws + 593152);             // 8192
  unsigned short* qt  = (unsigned short*)(ws + 601344);    // 4718592
  unsigned char* idx  = (unsigned char*)(ws + 5319936);    // 131072
  int*   cnt          = (int*)(ws + 5451008);              // 8192
  float* agg          = (float*)(ws + 5459200);            // 3145728
  unsigned short* aggs= (unsigned short*)(ws + 8604928);   // 1572864
  unsigned short* tbuf= (unsigned short*)(ws + 10177792);  // 1572864

  float* outp = (float*)d_out;            // [2048][384]
  float* soft = outp + 786432;            // [2048][4096]

  hipMemsetAsync(ws + 5451008, 0, 8192 + 3145728, stream);   // cnt + agg

  k_w2  <<<384, 384, 0, stream>>>(qw, kw, qb, kb, w2f, u, b2v, qbkb);
  k_qtf <<<256, 384, 0, stream>>>(query, w2f, b2v, qt);
  k_bias<<<512, 256, 0, stream>>>(query, u, qbkb, bias);
  k_attn<<<dim3(16,32), 256, 0, stream>>>(qt, key, bias, soft, idx, cnt);
  k_agg <<<dim3(8,2,32), 192, 0, stream>>>(key, idx, agg);
  k_scale<<<2048, 384, 0, stream>>>(agg, cnt, aggs);
  k_out384<<<dim3(3,16), 256, 0, stream>>>(aggs, vw, vb, cnt, tbuf, nullptr, 0);
  k_out384<<<dim3(3,16), 256, 0, stream>>>(tbuf, pw, pb, cnt, nullptr, outp, 1);
}

// Round 3
// 604.456 us; speedup vs baseline: 1.1804x; 1.1804x over previous
//
#include <hip/hip_runtime.h>
#include <hip/hip_bf16.h>
#include <stdint.h>
#include <stddef.h>

// GroupViT assign-attention, MI355X/gfx950. All I/O fp32.
// Identities:
//   raw_attn = (q @ k_w) . key_n + q . k_b          -> no k-projection GEMM
//   fwd attn value = one_hot(argmax)/(cnt+1)        -> no v-projection GEMM
//   out_pre = (sum_assigned key_n)/(cnt+1) @ v_w^T + cnt/(cnt+1) v_b
// Logit precision: W2 fp32, q~ fp32 (VALU GEMM), q~ 3-way bf16 split,
// key 2-way split, 4-product MFMA -> logit err ~1e-5 pre-scale (= ref noise).
// R2 lesson: runtime index into register array (acc[mi][ni] w/ runtime ni)
// kills SROA -> acc lives in scratch -> 680 MB of HBM spill writes. All
// register-array indices MUST be compile-time constants.

using bf16 = __hip_bfloat16;
typedef __attribute__((ext_vector_type(4))) float f32x4;
typedef __attribute__((ext_vector_type(8))) short s16x8;
typedef __attribute__((ext_vector_type(4))) short s16x4;

#define B_  32
#define G_  64
#define N_  4096
#define C_  384
#define SCALE 0.05103103630798287f   // 384^-0.5

__device__ __forceinline__ float us2f(unsigned short u){
  union { unsigned int i; float f; } v; v.i = ((unsigned int)u) << 16; return v.f;
}
__device__ __forceinline__ unsigned short f2us(float f){
  bf16 h = __float2bfloat16(f);
  return __builtin_bit_cast(unsigned short, h);
}

__device__ __forceinline__ f32x4 mfma16(s16x8 a, s16x8 b, f32x4 c){
  return __builtin_amdgcn_mfma_f32_16x16x32_bf16(a, b, c, 0, 0, 0);
}

// Swizzled LDS layout for [rows][64] bf16 tiles: 16B granule q XOR'd with m&7.
__device__ __forceinline__ int loff(int m, int q){ return m*64 + ((q ^ (m & 7)) << 3); }

// Stage ROWS x 64 bf16 tile from row-major bf16 global (ld elements).
template<int ROWS>
__device__ __forceinline__ void stage64(short* lds, const unsigned short* g, int ld, int tid){
  #pragma unroll
  for (int j = 0; j < (ROWS*8)/256; ++j){
    int i = tid + j*256;
    int m = i >> 3, q = i & 7;
    s16x8 v = *(const s16x8*)(g + (size_t)m*ld + q*8);
    *(s16x8*)(lds + loff(m, q)) = v;
  }
}

// Stage ROWS x 64 tile from fp32 global, converting to bf16 (round-nearest).
template<int ROWS>
__device__ __forceinline__ void stage64f(short* lds, const float* g, int ld, int tid){
  #pragma unroll
  for (int j = 0; j < (ROWS*16)/256; ++j){
    int i = tid + j*256;
    int m = i >> 4, qq = i & 15;
    f32x4 v = *(const f32x4*)(g + (size_t)m*ld + qq*4);
    s16x4 h;
    #pragma unroll
    for (int r = 0; r < 4; ++r) h[r] = (short)f2us(v[r]);
    *(s16x4*)(lds + loff(m, qq >> 1) + (qq & 1)*4) = h;
  }
}

// A/B fragment: lane holds row (base + lane&15), k-granule ks*4 + (lane>>4).
__device__ __forceinline__ s16x8 fragld(const short* lds, int row, int ks, int lane){
  return *(const s16x8*)(lds + loff(row + (lane & 15), ks*4 + (lane >> 4)));
}

// ---------------- K0: W2[c][t] = sum_i qw[i,c]*kw[i,t] (fp32) + u, b2v, qbkb
__global__ __launch_bounds__(384) void k_w2(
    const float* __restrict__ qw, const float* __restrict__ kw,
    const float* __restrict__ qb, const float* __restrict__ kb,
    float* __restrict__ w2f, float* __restrict__ u,
    float* __restrict__ b2v, float* __restrict__ qbkb)
{
  int c0 = blockIdx.x*4, t = threadIdx.x;
  float acc[4] = {0.f, 0.f, 0.f, 0.f};
  for (int i = 0; i < 384; ++i){
    float kv = kw[i*384 + t];
    #pragma unroll
    for (int r = 0; r < 4; ++r)
      acc[r] = fmaf(qw[i*384 + c0 + r], kv, acc[r]);
  }
  #pragma unroll
  for (int r = 0; r < 4; ++r) w2f[(c0 + r)*384 + t] = acc[r];

  __shared__ float red[384];
  if (blockIdx.x == 0){
    float a = 0.f, bs = 0.f;
    #pragma unroll 8
    for (int i = 0; i < 384; ++i){
      a  = fmaf(qw[i*384 + t], kb[i], a);
      bs = fmaf(qb[i], kw[i*384 + t], bs);
    }
    u[t] = a; b2v[t] = bs;
    red[t] = qb[t] * kb[t];
    __syncthreads();
    for (int s = 192; s >= 3; s >>= 1){
      if (t < s) red[t] += red[t + s];
      __syncthreads();
    }
    if (t == 0) *qbkb = red[0] + red[1] + red[2];
  }
}

// ---------------- K1: q~ = (query @ W2 + b2) * scale, fp32 VALU, 3-way split
__global__ __launch_bounds__(384) void k_qtf(
    const float* __restrict__ query,   // [2048][384]
    const float* __restrict__ w2f,     // [c][t]
    const float* __restrict__ b2v,
    unsigned short* __restrict__ qt)   // [B][192][384]: rows g=hi, 64+g=mid, 128+g=lo
{
  __shared__ float qs[16*384];
  int m0 = blockIdx.x * 16, t = threadIdx.x;
  #pragma unroll
  for (int r = 0; r < 16; ++r) qs[r*384 + t] = query[(size_t)(m0 + r)*384 + t];
  __syncthreads();
  float acc[16];
  float b2 = b2v[t];
  #pragma unroll
  for (int r = 0; r < 16; ++r) acc[r] = b2;
  for (int c = 0; c < 384; ++c){
    float w = w2f[c*384 + t];
    #pragma unroll
    for (int r = 0; r < 16; ++r) acc[r] = fmaf(qs[r*384 + c], w, acc[r]);
  }
  #pragma unroll
  for (int r = 0; r < 16; ++r){
    int m = m0 + r, b = m >> 6, g = m & 63;
    float v = acc[r] * SCALE;
    unsigned short h = f2us(v);
    float rem = v - us2f(h);
    unsigned short md = f2us(rem);
    float rem2 = rem - us2f(md);
    unsigned short l = f2us(rem2);
    size_t base = ((size_t)b*192 + g)*384 + t;
    qt[base]                   = h;
    qt[base + (size_t)64*384]  = md;
    qt[base + (size_t)128*384] = l;
  }
}

// ---------------- K1b: bias[m] = scale*(query[m].u + q_b.k_b)
__global__ void k_bias(const float* __restrict__ query,
                       const float* __restrict__ u,
                       const float* __restrict__ qbkb,
                       float* __restrict__ bias)
{
  int lane = threadIdx.x & 63, w = threadIdx.x >> 6;
  int m = blockIdx.x*4 + w;
  float p = 0.f;
  #pragma unroll
  for (int j = 0; j < 6; ++j){
    int e = lane + 64*j;
    p = fmaf(query[(size_t)m*384 + e], u[e], p);
  }
  p += __shfl_xor(p, 1);  p += __shfl_xor(p, 2);  p += __shfl_xor(p, 4);
  p += __shfl_xor(p, 8);  p += __shfl_xor(p, 16); p += __shfl_xor(p, 32);
  if (lane == 0) bias[m] = SCALE * (p + *qbkb);
}

// ---------------- K2: logits (4-product split MFMA) + softmax(g) + argmax
__global__ __launch_bounds__(256, 2) void k_attn(
    const unsigned short* __restrict__ qt,    // [B][192][384] bf16
    const float* __restrict__ key,            // [B][N][C] fp32
    const float* __restrict__ bias,           // [B*64]
    float* __restrict__ soft,                 // [B][64][N] fp32
    unsigned char* __restrict__ idx,          // [B][N]
    int* __restrict__ cnt)                    // [B*64]
{
  __shared__ short As[192*64];   // q~ hi/mid/lo tiles
  __shared__ short Bs[256*64];   // key hi, then key lo
  int b = blockIdx.y, n0 = blockIdx.x*256;
  int tid = threadIdx.x, lane = tid & 63, w = tid >> 6;
  const unsigned short* qb = qt + (size_t)b*192*384;
  const float* kb = key + ((size_t)b*N_ + n0)*C_;
  f32x4 acc[4][4] = {};
  float biasv[16];
  #pragma unroll
  for (int mi = 0; mi < 4; ++mi)
    #pragma unroll
    for (int r = 0; r < 4; ++r)
      biasv[mi*4 + r] = bias[b*64 + mi*16 + ((lane >> 4) << 2) + r];

  for (int kk = 0; kk < 6; ++kk){
    stage64<192>(As, qb + kk*64, 384, tid);
    // stage key hi (fp32 -> bf16 RN)
    #pragma unroll
    for (int j = 0; j < 16; ++j){
      int i = tid + j*256, m = i >> 4, qq = i & 15;
      f32x4 v = *(const f32x4*)(kb + (size_t)m*C_ + kk*64 + qq*4);
      s16x4 h;
      #pragma unroll
      for (int r = 0; r < 4; ++r) h[r] = (short)f2us(v[r]);
      *(s16x4*)(Bs + loff(m, qq >> 1) + (qq & 1)*4) = h;
    }
    __syncthreads();
    // phase A: (qh + qm + ql) . kh
    #pragma unroll
    for (int ks = 0; ks < 2; ++ks){
      s16x8 bf4[4];
      #pragma unroll
      for (int ni = 0; ni < 4; ++ni) bf4[ni] = fragld(Bs, w*64 + ni*16, ks, lane);
      #pragma unroll
      for (int mi = 0; mi < 4; ++mi){
        s16x8 a0 = fragld(As, mi*16, ks, lane);
        s16x8 a1 = fragld(As, 64 + mi*16, ks, lane);
        s16x8 a2 = fragld(As, 128 + mi*16, ks, lane);
        #pragma unroll
        for (int ni = 0; ni < 4; ++ni){
          acc[mi][ni] = mfma16(a0, bf4[ni], acc[mi][ni]);
          acc[mi][ni] = mfma16(a1, bf4[ni], acc[mi][ni]);
          acc[mi][ni] = mfma16(a2, bf4[ni], acc[mi][ni]);
        }
      }
    }
    __syncthreads();
    // stage key lo = f - bf16(f); re-read from global (tile is L2/L1-warm)
    #pragma unroll
    for (int j = 0; j < 16; ++j){
      int i = tid + j*256, m = i >> 4, qq = i & 15;
      f32x4 v = *(const f32x4*)(kb + (size_t)m*C_ + kk*64 + qq*4);
      s16x4 l;
      #pragma unroll
      for (int r = 0; r < 4; ++r){
        float f = v[r];
        l[r] = (short)f2us(f - us2f(f2us(f)));
      }
      *(s16x4*)(Bs + loff(m, qq >> 1) + (qq & 1)*4) = l;
    }
    __syncthreads();
    // phase B: qh . kl
    #pragma unroll
    for (int ks = 0; ks < 2; ++ks){
      s16x8 bf4[4];
      #pragma unroll
      for (int ni = 0; ni < 4; ++ni) bf4[ni] = fragld(Bs, w*64 + ni*16, ks, lane);
      #pragma unroll
      for (int mi = 0; mi < 4; ++mi){
        s16x8 a0 = fragld(As, mi*16, ks, lane);
        #pragma unroll
        for (int ni = 0; ni < 4; ++ni)
          acc[mi][ni] = mfma16(a0, bf4[ni], acc[mi][ni]);
      }
    }
    __syncthreads();
  }

  // Epilogue: FULLY unrolled (all register-array indices constant)
  #pragma unroll
  for (int ni = 0; ni < 4; ++ni){
    int col = n0 + w*64 + ni*16 + (lane & 15);
    float sg[16];
    float mx = -3.4e38f;
    #pragma unroll
    for (int i = 0; i < 16; ++i){
      float v = acc[i >> 2][ni][i & 3] + biasv[i];
      sg[i] = v; mx = fmaxf(mx, v);
    }
    mx = fmaxf(mx, __shfl_xor(mx, 16));
    mx = fmaxf(mx, __shfl_xor(mx, 32));
    float sum = 0.f, bv = -3.4e38f; int bg = 0;
    #pragma unroll
    for (int i = 0; i < 16; ++i){
      int g = (i >> 2)*16 + ((lane >> 4) << 2) + (i & 3);
      float v = sg[i];
      if (v > bv){ bv = v; bg = g; }
      float e = __expf(v - mx);
      sg[i] = e; sum += e;
    }
    sum += __shfl_xor(sum, 16);
    sum += __shfl_xor(sum, 32);
    { float ov = __shfl_xor(bv, 16); int og = __shfl_xor(bg, 16);
      if (ov > bv || (ov == bv && og < bg)){ bv = ov; bg = og; } }
    { float ov = __shfl_xor(bv, 32); int og = __shfl_xor(bg, 32);
      if (ov > bv || (ov == bv && og < bg)){ bv = ov; bg = og; } }
    float inv = 1.0f / sum;
    #pragma unroll
    for (int i = 0; i < 16; ++i){
      int g = (i >> 2)*16 + ((lane >> 4) << 2) + (i & 3);
      soft[(size_t)(b*64 + g)*N_ + col] = sg[i] * inv;
    }
    if ((lane >> 4) == 0){
      idx[(size_t)b*N_ + col] = (unsigned char)bg;
      atomicAdd(&cnt[b*64 + bg], 1);
    }
  }
}

// ---------------- K3: agg[b,g,c] = sum of key rows assigned to g
__global__ __launch_bounds__(192) void k_agg(
    const float* __restrict__ key,
    const unsigned char* __restrict__ idx,
    float* __restrict__ agg)                  // [2048][384] fp32, pre-zeroed
{
  __shared__ float accs[64*192];
  __shared__ unsigned char gl[256];
  int ch = blockIdx.x;       // 0..15 (256-row chunk)
  int h  = blockIdx.y;       // 0..1 (channel half)
  int b  = blockIdx.z;
  int t  = threadIdx.x;      // channel h*192+t
  for (int i = t; i < 64*192; i += 192) accs[i] = 0.f;
  const unsigned char* ib = idx + (size_t)b*N_ + ch*256;
  if (t < 64) ((unsigned int*)gl)[t] = ((const unsigned int*)ib)[t];
  __syncthreads();
  const float* kp = key + ((size_t)b*N_ + ch*256)*C_ + h*192 + t;
  for (int n0b = 0; n0b < 256; n0b += 8){
    float v[8];
    #pragma unroll
    for (int r = 0; r < 8; ++r) v[r] = kp[(size_t)(n0b + r)*C_];
    #pragma unroll
    for (int r = 0; r < 8; ++r) accs[(int)gl[n0b + r]*192 + t] += v[r];
  }
  __syncthreads();
  float* ab = agg + (size_t)b*64*C_ + h*192 + t;
  for (int gg = 0; gg < 64; ++gg)
    atomicAdd(ab + (size_t)gg*C_, accs[gg*192 + t]);
}

// ---------------- K3b: aggs = bf16(agg/(cnt+1))
__global__ void k_scale(const float* __restrict__ agg,
                        const int* __restrict__ cnt,
                        unsigned short* __restrict__ aggs)
{
  int m = blockIdx.x, t = threadIdx.x;
  float inv = 1.f / ((float)cnt[m] + 1.f);
  aggs[(size_t)m*384 + t] = f2us(agg[(size_t)m*384 + t] * inv);
}

// ---------------- K4: out = A @ W^T + bias-term (mode 0: +cw*v_b -> bf16 tbuf;
//                                                 mode 1: +p_b   -> fp32 out)
__global__ __launch_bounds__(256) void k_out384(
    const unsigned short* __restrict__ A,     // [2048][384] bf16
    const float* __restrict__ Wm,             // [384][384] fp32, [n][k]
    const float* __restrict__ bvec,           // [384] fp32
    const int* __restrict__ cnt,
    unsigned short* __restrict__ outb,
    float* __restrict__ outf,
    int mode)
{
  __shared__ short As[128*64];
  __shared__ short Bs[128*64];
  __shared__ float cwl[128];
  int m0 = blockIdx.y*128, nn0 = blockIdx.x*128;
  int tid = threadIdx.x, lane = tid & 63, w = tid >> 6;
  f32x4 acc[8][2] = {};
  for (int kk = 0; kk < 6; ++kk){
    stage64<128>(As, A + (size_t)m0*384 + kk*64, 384, tid);
    stage64f<128>(Bs, Wm + (size_t)nn0*384 + kk*64, 384, tid);
    __syncthreads();
    #pragma unroll
    for (int ks = 0; ks < 2; ++ks){
      s16x8 af[8], bfr[2];
      #pragma unroll
      for (int mi = 0; mi < 8; ++mi) af[mi] = fragld(As, mi*16, ks, lane);
      #pragma unroll
      for (int ni = 0; ni < 2; ++ni) bfr[ni] = fragld(Bs, w*32 + ni*16, ks, lane);
      #pragma unroll
      for (int mi = 0; mi < 8; ++mi)
        #pragma unroll
        for (int ni = 0; ni < 2; ++ni)
          acc[mi][ni] = mfma16(af[mi], bfr[ni], acc[mi][ni]);
    }
    __syncthreads();
  }
  if (mode == 0 && tid < 128){
    float c = (float)cnt[m0 + tid];
    cwl[tid] = c / (c + 1.f);
  }
  __syncthreads();
  #pragma unroll
  for (int ni = 0; ni < 2; ++ni){
    int n = nn0 + w*32 + ni*16 + (lane & 15);
    float bb = bvec[n];
    #pragma unroll
    for (int mi = 0; mi < 8; ++mi){
      #pragma unroll
      for (int r = 0; r < 4; ++r){
        int ml = mi*16 + ((lane >> 4) << 2) + r;
        float v = acc[mi][ni][r];
        if (mode == 0){
          v += cwl[ml] * bb;
          outb[(size_t)(m0 + ml)*384 + n] = f2us(v);
        } else {
          outf[(size_t)(m0 + ml)*384 + n] = v + bb;
        }
      }
    }
  }
}

extern "C" void kernel_launch(void* const* d_in, const int* in_sizes, int n_in,
                              void* d_out, int out_size, void* d_ws, size_t ws_size,
                              hipStream_t stream)
{
  const float* query = (const float*)d_in[0];
  const float* key   = (const float*)d_in[1];
  const float* qw    = (const float*)d_in[2];
  const float* qb    = (const float*)d_in[3];
  const float* kw    = (const float*)d_in[4];
  const float* kb    = (const float*)d_in[5];
  const float* vw    = (const float*)d_in[6];
  const float* vb    = (const float*)d_in[7];
  const float* pw    = (const float*)d_in[8];
  const float* pb    = (const float*)d_in[9];

  char* ws = (char*)d_ws;
  float* w2f          = (float*)(ws + 0);                  // 589824
  float* u            = (float*)(ws + 589824);             // 1536
  float* b2v          = (float*)(ws + 591360);             // 1536
  float* qbkb         = (float*)(ws + 592896);             // 256
  float* bias         = (float*)(ws + 593152);             // 8192
  unsigned short* qt  = (unsigned short*)(ws + 601344);    // 4718592
  unsigned char* idx  = (unsigned char*)(ws + 5319936);    // 131072
  int*   cnt          = (int*)(ws + 5451008);              // 8192
  float* agg          = (float*)(ws + 5459200);            // 3145728
  unsigned short* aggs= (unsigned short*)(ws + 8604928);   // 1572864
  unsigned short* tbuf= (unsigned short*)(ws + 10177792);  // 1572864

  float* outp = (float*)d_out;            // [2048][384]
  float* soft = outp + 786432;            // [2048][4096]

  hipMemsetAsync(ws + 5451008, 0, 8192 + 3145728, stream);   // cnt + agg

  k_w2  <<<96, 384, 0, stream>>>(qw, kw, qb, kb, w2f, u, b2v, qbkb);
  k_qtf <<<128, 384, 0, stream>>>(query, w2f, b2v, qt);
  k_bias<<<512, 256, 0, stream>>>(query, u, qbkb, bias);
  k_attn<<<dim3(16,32), 256, 0, stream>>>(qt, key, bias, soft, idx, cnt);
  k_agg <<<dim3(16,2,32), 192, 0, stream>>>(key, idx, agg);
  k_scale<<<2048, 384, 0, stream>>>(agg, cnt, aggs);
  k_out384<<<dim3(3,16), 256, 0, stream>>>(aggs, vw, vb, cnt, tbuf, nullptr, 0);
  k_out384<<<dim3(3,16), 256, 0, stream>>>(tbuf, pw, pb, cnt, nullptr, outp, 1);
}

// Round 4
// 543.284 us; speedup vs baseline: 1.3134x; 1.1126x over previous
//
#include <hip/hip_runtime.h>
#include <hip/hip_bf16.h>
#include <stdint.h>
#include <stddef.h>

// GroupViT assign-attention, MI355X/gfx950. All I/O fp32.
// Identities:
//   raw_attn = (q @ k_w) . key_n + q . k_b          -> no k-projection GEMM
//   fwd attn value = one_hot(argmax)/(cnt+1)        -> no v-projection GEMM
//   out_pre = (sum_assigned key_n)/(cnt+1) @ v_w^T + cnt/(cnt+1) v_b
// Logit precision: W2 fp32, q~ fp32 (VALU GEMM), q~ 3-way bf16 split,
// key 2-way split, 4-product MFMA -> logit err ~1e-5 pre-scale (= ref noise).
// R2 lesson: runtime index into register array kills SROA -> scratch spill.
// R3 lesson: 12.6M fp32 atomicAdds cost >100us -> counting-sort (perm) +
//   gather instead; k_attn barrier lockstep -> prefetch key into regs.

using bf16 = __hip_bfloat16;
typedef __attribute__((ext_vector_type(4))) float f32x4;
typedef __attribute__((ext_vector_type(8))) short s16x8;
typedef __attribute__((ext_vector_type(4))) short s16x4;

#define B_  32
#define G_  64
#define N_  4096
#define C_  384
#define CAP 2048   // perm bucket capacity (counts ~64 avg; 2048 is >>max)
#define SCALE 0.05103103630798287f   // 384^-0.5

__device__ __forceinline__ float us2f(unsigned short u){
  union { unsigned int i; float f; } v; v.i = ((unsigned int)u) << 16; return v.f;
}
__device__ __forceinline__ unsigned short f2us(float f){
  bf16 h = __float2bfloat16(f);
  return __builtin_bit_cast(unsigned short, h);
}

__device__ __forceinline__ f32x4 mfma16(s16x8 a, s16x8 b, f32x4 c){
  return __builtin_amdgcn_mfma_f32_16x16x32_bf16(a, b, c, 0, 0, 0);
}

// Swizzled LDS layout for [rows][64] bf16 tiles: 16B granule q XOR'd with m&7.
__device__ __forceinline__ int loff(int m, int q){ return m*64 + ((q ^ (m & 7)) << 3); }

// Stage ROWS x 64 bf16 tile from row-major bf16 global (ld elements).
template<int ROWS>
__device__ __forceinline__ void stage64(short* lds, const unsigned short* g, int ld, int tid){
  #pragma unroll
  for (int j = 0; j < (ROWS*8)/256; ++j){
    int i = tid + j*256;
    int m = i >> 3, q = i & 7;
    s16x8 v = *(const s16x8*)(g + (size_t)m*ld + q*8);
    *(s16x8*)(lds + loff(m, q)) = v;
  }
}

// Stage ROWS x 64 tile from fp32 global, converting to bf16 (round-nearest).
template<int ROWS>
__device__ __forceinline__ void stage64f(short* lds, const float* g, int ld, int tid){
  #pragma unroll
  for (int j = 0; j < (ROWS*16)/256; ++j){
    int i = tid + j*256;
    int m = i >> 4, qq = i & 15;
    f32x4 v = *(const f32x4*)(g + (size_t)m*ld + qq*4);
    s16x4 h;
    #pragma unroll
    for (int r = 0; r < 4; ++r) h[r] = (short)f2us(v[r]);
    *(s16x4*)(lds + loff(m, qq >> 1) + (qq & 1)*4) = h;
  }
}

// A/B fragment: lane holds row (base + lane&15), k-granule ks*4 + (lane>>4).
__device__ __forceinline__ s16x8 fragld(const short* lds, int row, int ks, int lane){
  return *(const s16x8*)(lds + loff(row + (lane & 15), ks*4 + (lane >> 4)));
}

// ---------------- K0: W2[c][t] = sum_i qw[i,c]*kw[i,t] (fp32) + u, b2v, qbkb
__global__ __launch_bounds__(384) void k_w2(
    const float* __restrict__ qw, const float* __restrict__ kw,
    const float* __restrict__ qb, const float* __restrict__ kb,
    float* __restrict__ w2f, float* __restrict__ u,
    float* __restrict__ b2v, float* __restrict__ qbkb)
{
  int c0 = blockIdx.x*4, t = threadIdx.x;
  float acc[4] = {0.f, 0.f, 0.f, 0.f};
  for (int i = 0; i < 384; ++i){
    float kv = kw[i*384 + t];
    #pragma unroll
    for (int r = 0; r < 4; ++r)
      acc[r] = fmaf(qw[i*384 + c0 + r], kv, acc[r]);
  }
  #pragma unroll
  for (int r = 0; r < 4; ++r) w2f[(c0 + r)*384 + t] = acc[r];

  __shared__ float red[384];
  if (blockIdx.x == 0){
    float a = 0.f, bs = 0.f;
    #pragma unroll 8
    for (int i = 0; i < 384; ++i){
      a  = fmaf(qw[i*384 + t], kb[i], a);
      bs = fmaf(qb[i], kw[i*384 + t], bs);
    }
    u[t] = a; b2v[t] = bs;
    red[t] = qb[t] * kb[t];
    __syncthreads();
    for (int s = 192; s >= 3; s >>= 1){
      if (t < s) red[t] += red[t + s];
      __syncthreads();
    }
    if (t == 0) *qbkb = red[0] + red[1] + red[2];
  }
}

// ---------------- K1: q~ = (query @ W2 + b2) * scale, fp32 VALU, 3-way split
__global__ __launch_bounds__(384) void k_qtf(
    const float* __restrict__ query,   // [2048][384]
    const float* __restrict__ w2f,     // [c][t]
    const float* __restrict__ b2v,
    unsigned short* __restrict__ qt)   // [B][192][384]: rows g=hi, 64+g=mid, 128+g=lo
{
  __shared__ float qs[16*384];
  int m0 = blockIdx.x * 16, t = threadIdx.x;
  #pragma unroll
  for (int r = 0; r < 16; ++r) qs[r*384 + t] = query[(size_t)(m0 + r)*384 + t];
  __syncthreads();
  float acc[16];
  float b2 = b2v[t];
  #pragma unroll
  for (int r = 0; r < 16; ++r) acc[r] = b2;
  for (int c = 0; c < 384; ++c){
    float w = w2f[c*384 + t];
    #pragma unroll
    for (int r = 0; r < 16; ++r) acc[r] = fmaf(qs[r*384 + c], w, acc[r]);
  }
  #pragma unroll
  for (int r = 0; r < 16; ++r){
    int m = m0 + r, b = m >> 6, g = m & 63;
    float v = acc[r] * SCALE;
    unsigned short h = f2us(v);
    float rem = v - us2f(h);
    unsigned short md = f2us(rem);
    float rem2 = rem - us2f(md);
    unsigned short l = f2us(rem2);
    size_t base = ((size_t)b*192 + g)*384 + t;
    qt[base]                   = h;
    qt[base + (size_t)64*384]  = md;
    qt[base + (size_t)128*384] = l;
  }
}

// ---------------- K1b: bias[m] = scale*(query[m].u + q_b.k_b)
__global__ void k_bias(const float* __restrict__ query,
                       const float* __restrict__ u,
                       const float* __restrict__ qbkb,
                       float* __restrict__ bias)
{
  int lane = threadIdx.x & 63, w = threadIdx.x >> 6;
  int m = blockIdx.x*4 + w;
  float p = 0.f;
  #pragma unroll
  for (int j = 0; j < 6; ++j){
    int e = lane + 64*j;
    p = fmaf(query[(size_t)m*384 + e], u[e], p);
  }
  p += __shfl_xor(p, 1);  p += __shfl_xor(p, 2);  p += __shfl_xor(p, 4);
  p += __shfl_xor(p, 8);  p += __shfl_xor(p, 16); p += __shfl_xor(p, 32);
  if (lane == 0) bias[m] = SCALE * (p + *qbkb);
}

// ---------------- K2: logits (4-product split MFMA) + softmax(g) + argmax
// Pipelined: key tile kept in regs, next tile's HBM loads issued before MFMA.
__global__ __launch_bounds__(256, 2) void k_attn(
    const unsigned short* __restrict__ qt,    // [B][192][384] bf16
    const float* __restrict__ key,            // [B][N][C] fp32
    const float* __restrict__ bias,           // [B*64]
    float* __restrict__ soft,                 // [B][64][N] fp32
    unsigned short* __restrict__ perm,        // [B*64][CAP]
    int* __restrict__ cnt)                    // [B*64]
{
  __shared__ short As[192*64];   // q~ hi/mid/lo tiles
  __shared__ short Bs[256*64];   // key hi, then key lo
  int b = blockIdx.y, n0 = blockIdx.x*256;
  int tid = threadIdx.x, lane = tid & 63, w = tid >> 6;
  const unsigned short* qb = qt + (size_t)b*192*384;
  const float* kb = key + ((size_t)b*N_ + n0)*C_;
  f32x4 acc[4][4] = {};
  float biasv[16];
  #pragma unroll
  for (int mi = 0; mi < 4; ++mi)
    #pragma unroll
    for (int r = 0; r < 4; ++r)
      biasv[mi*4 + r] = bias[b*64 + mi*16 + ((lane >> 4) << 2) + r];

  f32x4 kv[16];
  auto load_kv = [&](int kk){
    #pragma unroll
    for (int j = 0; j < 16; ++j){
      int i = tid + j*256, m = i >> 4, qq = i & 15;
      kv[j] = *(const f32x4*)(kb + (size_t)m*C_ + kk*64 + qq*4);
    }
  };
  load_kv(0);

  for (int kk = 0; kk < 6; ++kk){
    // split kv -> hi/lo bf16 regs (kv dead after this)
    s16x4 hi[16], lo[16];
    #pragma unroll
    for (int j = 0; j < 16; ++j){
      #pragma unroll
      for (int r = 0; r < 4; ++r){
        float f = kv[j][r];
        unsigned short h = f2us(f);
        hi[j][r] = (short)h;
        lo[j][r] = (short)f2us(f - us2f(h));
      }
    }
    #pragma unroll
    for (int j = 0; j < 16; ++j){
      int i = tid + j*256, m = i >> 4, qq = i & 15;
      *(s16x4*)(Bs + loff(m, qq >> 1) + (qq & 1)*4) = hi[j];
    }
    stage64<192>(As, qb + kk*64, 384, tid);
    __syncthreads();
    if (kk < 5) load_kv(kk + 1);   // HBM loads fly across phases A+B
    // phase A: (qh + qm + ql) . kh
    #pragma unroll
    for (int ks = 0; ks < 2; ++ks){
      s16x8 bf4[4];
      #pragma unroll
      for (int ni = 0; ni < 4; ++ni) bf4[ni] = fragld(Bs, w*64 + ni*16, ks, lane);
      #pragma unroll
      for (int mi = 0; mi < 4; ++mi){
        s16x8 a0 = fragld(As, mi*16, ks, lane);
        s16x8 a1 = fragld(As, 64 + mi*16, ks, lane);
        s16x8 a2 = fragld(As, 128 + mi*16, ks, lane);
        #pragma unroll
        for (int ni = 0; ni < 4; ++ni){
          acc[mi][ni] = mfma16(a0, bf4[ni], acc[mi][ni]);
          acc[mi][ni] = mfma16(a1, bf4[ni], acc[mi][ni]);
          acc[mi][ni] = mfma16(a2, bf4[ni], acc[mi][ni]);
        }
      }
    }
    __syncthreads();
    #pragma unroll
    for (int j = 0; j < 16; ++j){
      int i = tid + j*256, m = i >> 4, qq = i & 15;
      *(s16x4*)(Bs + loff(m, qq >> 1) + (qq & 1)*4) = lo[j];
    }
    __syncthreads();
    // phase B: qh . kl
    #pragma unroll
    for (int ks = 0; ks < 2; ++ks){
      s16x8 bf4[4];
      #pragma unroll
      for (int ni = 0; ni < 4; ++ni) bf4[ni] = fragld(Bs, w*64 + ni*16, ks, lane);
      #pragma unroll
      for (int mi = 0; mi < 4; ++mi){
        s16x8 a0 = fragld(As, mi*16, ks, lane);
        #pragma unroll
        for (int ni = 0; ni < 4; ++ni)
          acc[mi][ni] = mfma16(a0, bf4[ni], acc[mi][ni]);
      }
    }
    __syncthreads();
  }

  // Epilogue: FULLY unrolled (all register-array indices constant)
  #pragma unroll
  for (int ni = 0; ni < 4; ++ni){
    int col = n0 + w*64 + ni*16 + (lane & 15);
    float sg[16];
    float mx = -3.4e38f;
    #pragma unroll
    for (int i = 0; i < 16; ++i){
      float v = acc[i >> 2][ni][i & 3] + biasv[i];
      sg[i] = v; mx = fmaxf(mx, v);
    }
    mx = fmaxf(mx, __shfl_xor(mx, 16));
    mx = fmaxf(mx, __shfl_xor(mx, 32));
    float sum = 0.f, bv = -3.4e38f; int bg = 0;
    #pragma unroll
    for (int i = 0; i < 16; ++i){
      int g = (i >> 2)*16 + ((lane >> 4) << 2) + (i & 3);
      float v = sg[i];
      if (v > bv){ bv = v; bg = g; }
      float e = __expf(v - mx);
      sg[i] = e; sum += e;
    }
    sum += __shfl_xor(sum, 16);
    sum += __shfl_xor(sum, 32);
    { float ov = __shfl_xor(bv, 16); int og = __shfl_xor(bg, 16);
      if (ov > bv || (ov == bv && og < bg)){ bv = ov; bg = og; } }
    { float ov = __shfl_xor(bv, 32); int og = __shfl_xor(bg, 32);
      if (ov > bv || (ov == bv && og < bg)){ bv = ov; bg = og; } }
    float inv = 1.0f / sum;
    #pragma unroll
    for (int i = 0; i < 16; ++i){
      int g = (i >> 2)*16 + ((lane >> 4) << 2) + (i & 3);
      soft[(size_t)(b*64 + g)*N_ + col] = sg[i] * inv;
    }
    if ((lane >> 4) == 0){
      int old = atomicAdd(&cnt[b*64 + bg], 1);
      if (old < CAP) perm[(size_t)(b*64 + bg)*CAP + old] = (unsigned short)col;
    }
  }
}

// ---------------- K3: per-(b,g) gather-sum of assigned key rows -> aggs bf16
__global__ __launch_bounds__(384) void k_agg2(
    const float* __restrict__ key,
    const unsigned short* __restrict__ perm,
    const int* __restrict__ cnt,
    unsigned short* __restrict__ aggs)        // [2048][384] bf16
{
  __shared__ unsigned short pbuf[CAP];
  int m = blockIdx.x;            // b*64 + g
  int b = m >> 6, t = threadIdx.x;
  int cn = cnt[m];
  int rows = cn < CAP ? cn : CAP;
  for (int i = t; i < rows; i += 384) pbuf[i] = perm[(size_t)m*CAP + i];
  __syncthreads();
  const float* kb = key + (size_t)b*N_*C_ + t;
  float s = 0.f;
  int r = 0;
  for (; r + 4 <= rows; r += 4){
    float v0 = kb[(size_t)pbuf[r+0]*C_];
    float v1 = kb[(size_t)pbuf[r+1]*C_];
    float v2 = kb[(size_t)pbuf[r+2]*C_];
    float v3 = kb[(size_t)pbuf[r+3]*C_];
    s += v0 + v1 + v2 + v3;
  }
  for (; r < rows; ++r) s += kb[(size_t)pbuf[r]*C_];
  aggs[(size_t)m*C_ + t] = f2us(s / ((float)cn + 1.f));
}

// ---------------- K4: out = A @ W^T + bias-term (mode 0: +cw*v_b -> bf16 tbuf;
//                                                 mode 1: +p_b   -> fp32 out)
__global__ __launch_bounds__(256) void k_out384(
    const unsigned short* __restrict__ A,     // [2048][384] bf16
    const float* __restrict__ Wm,             // [384][384] fp32, [n][k]
    const float* __restrict__ bvec,           // [384] fp32
    const int* __restrict__ cnt,
    unsigned short* __restrict__ outb,
    float* __restrict__ outf,
    int mode)
{
  __shared__ short As[128*64];
  __shared__ short Bs[128*64];
  __shared__ float cwl[128];
  int m0 = blockIdx.y*128, nn0 = blockIdx.x*128;
  int tid = threadIdx.x, lane = tid & 63, w = tid >> 6;
  f32x4 acc[8][2] = {};
  for (int kk = 0; kk < 6; ++kk){
    stage64<128>(As, A + (size_t)m0*384 + kk*64, 384, tid);
    stage64f<128>(Bs, Wm + (size_t)nn0*384 + kk*64, 384, tid);
    __syncthreads();
    #pragma unroll
    for (int ks = 0; ks < 2; ++ks){
      s16x8 af[8], bfr[2];
      #pragma unroll
      for (int mi = 0; mi < 8; ++mi) af[mi] = fragld(As, mi*16, ks, lane);
      #pragma unroll
      for (int ni = 0; ni < 2; ++ni) bfr[ni] = fragld(Bs, w*32 + ni*16, ks, lane);
      #pragma unroll
      for (int mi = 0; mi < 8; ++mi)
        #pragma unroll
        for (int ni = 0; ni < 2; ++ni)
          acc[mi][ni] = mfma16(af[mi], bfr[ni], acc[mi][ni]);
    }
    __syncthreads();
  }
  if (mode == 0 && tid < 128){
    float c = (float)cnt[m0 + tid];
    cwl[tid] = c / (c + 1.f);
  }
  __syncthreads();
  #pragma unroll
  for (int ni = 0; ni < 2; ++ni){
    int n = nn0 + w*32 + ni*16 + (lane & 15);
    float bb = bvec[n];
    #pragma unroll
    for (int mi = 0; mi < 8; ++mi){
      #pragma unroll
      for (int r = 0; r < 4; ++r){
        int ml = mi*16 + ((lane >> 4) << 2) + r;
        float v = acc[mi][ni][r];
        if (mode == 0){
          v += cwl[ml] * bb;
          outb[(size_t)(m0 + ml)*384 + n] = f2us(v);
        } else {
          outf[(size_t)(m0 + ml)*384 + n] = v + bb;
        }
      }
    }
  }
}

extern "C" void kernel_launch(void* const* d_in, const int* in_sizes, int n_in,
                              void* d_out, int out_size, void* d_ws, size_t ws_size,
                              hipStream_t stream)
{
  const float* query = (const float*)d_in[0];
  const float* key   = (const float*)d_in[1];
  const float* qw    = (const float*)d_in[2];
  const float* qb    = (const float*)d_in[3];
  const float* kw    = (const float*)d_in[4];
  const float* kb    = (const float*)d_in[5];
  const float* vw    = (const float*)d_in[6];
  const float* vb    = (const float*)d_in[7];
  const float* pw    = (const float*)d_in[8];
  const float* pb    = (const float*)d_in[9];

  char* ws = (char*)d_ws;
  float* w2f           = (float*)(ws + 0);                  // 589824
  float* u             = (float*)(ws + 589824);             // 1536
  float* b2v           = (float*)(ws + 591360);             // 1536
  float* qbkb          = (float*)(ws + 592896);             // 256
  float* bias          = (float*)(ws + 593152);             // 8192
  unsigned short* qt   = (unsigned short*)(ws + 601344);    // 4718592
  int*   cnt           = (int*)(ws + 5319936);              // 8192
  unsigned short* perm = (unsigned short*)(ws + 5328128);   // 8388608 (2048 buckets x CAP u16)
  unsigned short* aggs = (unsigned short*)(ws + 13716736);  // 1572864
  unsigned short* tbuf = (unsigned short*)(ws + 15289600);  // 1572864 -> ends 16862464

  float* outp = (float*)d_out;            // [2048][384]
  float* soft = outp + 786432;            // [2048][4096]

  hipMemsetAsync(cnt, 0, 8192, stream);

  k_w2  <<<96, 384, 0, stream>>>(qw, kw, qb, kb, w2f, u, b2v, qbkb);
  k_qtf <<<128, 384, 0, stream>>>(query, w2f, b2v, qt);
  k_bias<<<512, 256, 0, stream>>>(query, u, qbkb, bias);
  k_attn<<<dim3(16,32), 256, 0, stream>>>(qt, key, bias, soft, perm, cnt);
  k_agg2<<<2048, 384, 0, stream>>>(key, perm, cnt, aggs);
  k_out384<<<dim3(3,16), 256, 0, stream>>>(aggs, vw, vb, cnt, tbuf, nullptr, 0);
  k_out384<<<dim3(3,16), 256, 0, stream>>>(tbuf, pw, pb, cnt, nullptr, outp, 1);
}